// Round 13
// baseline (351.791 us; speedup 1.0000x reference)
//
#include <hip/hip_runtime.h>
#include <hip/hip_bf16.h>

typedef __attribute__((ext_vector_type(8))) short short8;
typedef __attribute__((ext_vector_type(4))) float f32x4;
typedef __attribute__((ext_vector_type(2))) float f32x2;

// ---- workspace layout (bytes) ----
#define WS_ZE     0u
#define WS_ZELO   (1u<<20)
#define WS_B1H    (2u<<20)
#define WS_B1L    (3u<<20)
#define WS_B2     (4u<<20)
#define WS_ZN2    (5u<<20)
#define WS_BS2    ((5u<<20)+32768u)
#define WS_ZQP    (6u<<20)

__device__ __forceinline__ unsigned short f2bf(float x) {
  __hip_bfloat16 h = __float2bfloat16(x);
  return __builtin_bit_cast(unsigned short, h);
}
__device__ __forceinline__ float bf2f(unsigned short u) {
  union { unsigned int i; float f; } x; x.i = ((unsigned int)u) << 16; return x.f;
}
// LDS-only barrier: does NOT drain vmcnt -> global stores stay in flight
__device__ __forceinline__ void lds_barrier() {
  asm volatile("s_waitcnt lgkmcnt(0)" ::: "memory");
  __builtin_amdgcn_s_barrier();
}

// ---------------- prep: ze -> bf16 hi/lo + row norms ----------------
__global__ __launch_bounds__(256) void prep_ze_k(const float* __restrict__ ze,
                                                 char* __restrict__ ws) {
  int t = blockIdx.x * 256 + threadIdx.x;
  if (t >= 8 * 1024) return;
  const f32x4* row = (const f32x4*)(ze + t * 64);
  unsigned short* dh = (unsigned short*)(ws + WS_ZE) + t * 64;
  unsigned short* dl = (unsigned short*)(ws + WS_ZELO) + t * 64;
  float s = 0.f;
#pragma unroll
  for (int c = 0; c < 8; ++c) {
    const f32x4 v0 = row[2 * c], v1 = row[2 * c + 1];
    union { unsigned short u[8]; short8 v; } H, L;
#pragma unroll
    for (int r = 0; r < 4; ++r) {
      float a = v0[r]; s += a * a;
      unsigned short h = f2bf(a); H.u[r] = h; L.u[r] = f2bf(a - bf2f(h));
      float b = v1[r]; s += b * b;
      unsigned short h2 = f2bf(b); H.u[4 + r] = h2; L.u[4 + r] = f2bf(b - bf2f(h2));
    }
    *(short8*)(dh + c * 8) = H.v;
    *(short8*)(dl + c * 8) = L.v;
  }
  ((float*)(ws + WS_ZN2))[t] = s;
}

// ---------------- prep: book norms + precision ----------------
__global__ __launch_bounds__(256) void prep_bnorm_k(const float* __restrict__ books,
                                                    const float* __restrict__ lpq,
                                                    char* __restrict__ ws,
                                                    float* __restrict__ d_out) {
  int t = blockIdx.x * 256 + threadIdx.x;
  if (t == 0) d_out[524288] = 0.5f / fmaxf(expf(lpq[0]), 1e-10f);
  if (t >= 16 * 512) return;
  const f32x4* row = (const f32x4*)(books + t * 64);
  float s = 0.f;
#pragma unroll
  for (int c = 0; c < 16; ++c) {
    const f32x4 v = row[c];
#pragma unroll
    for (int r = 0; r < 4; ++r) s += v[r] * v[r];
  }
  ((float*)(ws + WS_BS2))[t] = s;
}

// ---------------- prep: matmul1 A-frag images ----------------
__global__ __launch_bounds__(256) void prep_b1_k(const float* __restrict__ books,
                                                 char* __restrict__ ws) {
  int t = blockIdx.x * 256 + threadIdx.x;
  const int sl = t & 15, g = (t >> 4) & 3, f = (t >> 6) & 1, tt = (t >> 7) & 31, k = t >> 12;
  const float* src = books + ((k * 512 + tt * 16 + sl) * 64 + f * 32 + g * 8);
  const f32x4 v0 = *(const f32x4*)(src);
  const f32x4 v1 = *(const f32x4*)(src + 4);
  union { unsigned short u[8]; short8 v; } H, L;
#pragma unroll
  for (int r = 0; r < 4; ++r) {
    unsigned short h = f2bf(v0[r]); H.u[r] = h; L.u[r] = f2bf(v0[r] - bf2f(h));
    unsigned short h2 = f2bf(v1[r]); H.u[4 + r] = h2; L.u[4 + r] = f2bf(v1[r] - bf2f(h2));
  }
  const int off = (k * 32 + tt) * 2048 + f * 1024 + (sl + g * 16) * 16;
  *(short8*)(ws + WS_B1H + off) = H.v;
  *(short8*)(ws + WS_B1L + off) = L.v;
}

// ---------------- prep: matmul2 A-frag image ----------------
__global__ __launch_bounds__(256) void prep_b2_k(const float* __restrict__ books,
                                                 char* __restrict__ ws) {
  int t = blockIdx.x * 256 + threadIdx.x;
  const int l15 = t & 15, sub = (t >> 4) & 3, m = (t >> 6) & 3, w = (t >> 8) & 7,
            hh = (t >> 11) & 1, k = t >> 12;
  const float* src = books + ((k * 512 + hh * 256 + w * 32 + sub * 8) * 64 + m * 16 + l15);
  union { unsigned short u[8]; short8 v; } H;
#pragma unroll
  for (int j = 0; j < 8; ++j) H.u[j] = f2bf(src[j * 64]);
  *(short8*)(ws + WS_B2 + k * 65536 + ((hh * 8 + w) * 4 + m) * 1024 + (l15 + sub * 16) * 16) = H.v;
}

// ---------------- zq partial reduce ----------------
__global__ __launch_bounds__(256) void zq_red_k(const char* __restrict__ ws,
                                                float* __restrict__ d_out) {
  int t = blockIdx.x * 256 + threadIdx.x;
  const f32x4 a = *(const f32x4*)(ws + WS_ZQP + t * 16);
  const f32x4 b = *(const f32x4*)(ws + WS_ZQP + (1u << 21) + t * 16);
  *(f32x4*)(d_out + t * 4) = a + b;
}

// ---------------- main: reg-resident enc (in-wave shfl), 1 tiny barrier/iter ----------------
__global__ __launch_bounds__(512, 4)
void gvq_main(const float* __restrict__ gum, const float* __restrict__ cprobs,
              const float* __restrict__ lpq, char* __restrict__ ws,
              float* __restrict__ d_out) {
  __shared__ char lds[36864];
  f32x4* scrb = (f32x4*)(lds + 32768);   // 2 x 128 f32x4 (double-buffered)

  const int tid  = threadIdx.x;
  const int lane = tid & 63;
  const int wave = tid >> 6;
  const int l15  = lane & 15;
  const int g4   = lane >> 4;

  const int bid = blockIdx.x;      // 1024 blocks
  const int kg  = bid & 1;
  const int bt  = bid >> 1;
  const int b   = bt >> 6;
  const int n0  = (bt & 63) * 16;

  const float prec  = 0.5f / fmaxf(expf(lpq[0]), 1e-10f);
  const float prec2 = 2.0f * prec;
  const float C24   = 3.7751345442790977e-11f;   // exp(-24)

  const unsigned short* zh = (const unsigned short*)(ws + WS_ZE)   + (b * 1024 + n0 + l15) * 64;
  const unsigned short* zl = (const unsigned short*)(ws + WS_ZELO) + (b * 1024 + n0 + l15) * 64;
  const short8 zf0h = *(const short8*)(zh + g4 * 8);
  const short8 zf1h = *(const short8*)(zh + 32 + g4 * 8);
  const short8 zf0l = *(const short8*)(zl + g4 * 8);
  const short8 zf1l = *(const short8*)(zl + 32 + g4 * 8);
  const float zn2p = ((const float*)(ws + WS_ZN2))[b * 1024 + n0 + l15] * prec;

  f32x4 zacc[4] = {{0,0,0,0},{0,0,0,0},{0,0,0,0},{0,0,0,0}};
  const long gbase0 = ((long)(b * 16) * 1024 + (n0 + l15)) * 512 + wave * 64 + g4 * 4;

  // shfl sources for phase C B-frag: same l15, g4' = (g4&1)*2 (+1)
  const int srcLo = ((g4 & 1) * 2) * 16 + l15;
  const int srcHi = srcLo + 16;
  const bool selHi = (g4 >> 1) != 0;

#pragma unroll 1
  for (int kk = 0; kk < 8; ++kk) {
    const int k = kg * 8 + kk;
    const float cp = cprobs[b * 16 + k];
    const char* b1h = ws + WS_B1H + k * 65536;
    const char* b1l = ws + WS_B1L + k * 65536;
    const char* b2  = ws + WS_B2  + k * 65536;
    const float* bs2k = (const float*)(ws + WS_BS2) + k * 512;
    const long gb = gbase0 + (long)k * 524288;
    f32x4* scr = scrb + (kk & 1) * 128;

    // ---- gumbel loads (consumed in pass 2; covered by phase A) ----
    const float* up = gum + gb;
    f32x4 uu[4];
#pragma unroll
    for (int i = 0; i < 4; ++i) uu[i] = *(const f32x4*)(up + i * 16);

    // ---- phase A: logits in registers (3-term hi/lo bf16 MFMA) ----
    f32x4 lv[4];
#pragma unroll
    for (int i = 0; i < 4; ++i) {
      const int t = wave * 4 + i;
      const char* bh = b1h + t * 2048 + lane * 16;
      const char* bl = b1l + t * 2048 + lane * 16;
      const short8 a0h = *(const short8*)(bh);
      const short8 a1h = *(const short8*)(bh + 1024);
      const short8 a0l = *(const short8*)(bl);
      const short8 a1l = *(const short8*)(bl + 1024);
      f32x4 c = {0.f, 0.f, 0.f, 0.f};
      c = __builtin_amdgcn_mfma_f32_16x16x32_bf16(a0h, zf0h, c, 0, 0, 0);
      c = __builtin_amdgcn_mfma_f32_16x16x32_bf16(a1h, zf1h, c, 0, 0, 0);
      c = __builtin_amdgcn_mfma_f32_16x16x32_bf16(a0h, zf0l, c, 0, 0, 0);
      c = __builtin_amdgcn_mfma_f32_16x16x32_bf16(a1h, zf1l, c, 0, 0, 0);
      c = __builtin_amdgcn_mfma_f32_16x16x32_bf16(a0l, zf0h, c, 0, 0, 0);
      c = __builtin_amdgcn_mfma_f32_16x16x32_bf16(a1l, zf1h, c, 0, 0, 0);
      const f32x4 bs2v = *(const f32x4*)(bs2k + t * 16 + g4 * 4);
#pragma unroll
      for (int r = 0; r < 4; ++r)
        lv[i][r] = fmaf(c[r], prec2, fmaf(bs2v[r], -prec, -zn2p));
    }

    // ---- pass 1: wave-local max of lv (m2 bound-derived: 2*m1w+24) ----
    float m1w = -1e30f;
#pragma unroll
    for (int i = 0; i < 4; ++i)
#pragma unroll
      for (int r = 0; r < 4; ++r) m1w = fmaxf(m1w, lv[i][r]);
    m1w = fmaxf(m1w, __shfl_xor(m1w, 16));
    m1w = fmaxf(m1w, __shfl_xor(m1w, 32));

    // ---- pass 2: e1 (kept), e2 packed to registers (no LDS) ----
    float z1 = 0.f, z2 = 0.f;
    f32x4 e1v[4];
    int ew0[4], ew1[4];
#pragma unroll
    for (int i = 0; i < 4; ++i) {
      float e2x[4];
#pragma unroll
      for (int r = 0; r < 4; ++r) {
        const float e1 = __expf(lv[i][r] - m1w); e1v[i][r] = e1; z1 += e1;
        const float L  = 1e-10f - __logf(uu[i][r] + 1e-10f);
        const float rl = __builtin_amdgcn_rcpf(L);
        const float e2 = (e1 * e1) * (rl * rl) * C24;
        z2 += e2; e2x[r] = e2;
      }
      ew0[i] = (int)((((unsigned)f2bf(e2x[1])) << 16) | (unsigned)f2bf(e2x[0]));
      ew1[i] = (int)((((unsigned)f2bf(e2x[3])) << 16) | (unsigned)f2bf(e2x[2]));
    }
    z1 += __shfl_xor(z1, 16); z1 += __shfl_xor(z1, 32);
    z2 += __shfl_xor(z2, 16); z2 += __shfl_xor(z2, 32);
    if (g4 == 0) scr[wave * 16 + l15] = (f32x4){m1w, z1, z2, 0.f};
    lds_barrier();                 // only 2 KB scr is barrier-coupled

    // ---- merge across waves ----
    float m1, c1, ps, fh;
    {
      const f32x4 pa = scr[g4 * 16 + l15];
      const f32x4 pb = scr[(g4 + 4) * 16 + l15];
      m1 = fmaxf(pa.x, pb.x);
      m1 = fmaxf(m1, __shfl_xor(m1, 16)); m1 = fmaxf(m1, __shfl_xor(m1, 32));
      const float ea = __expf(pa.x - m1), eb = __expf(pb.x - m1);
      float zz1 = pa.y * ea + pb.y * eb;
      float zz2 = pa.z * ea * ea + pb.z * eb * eb;
      zz1 += __shfl_xor(zz1, 16); zz1 += __shfl_xor(zz1, 32);
      zz2 += __shfl_xor(zz2, 16); zz2 += __shfl_xor(zz2, 32);
      c1 = m1 + __logf(zz1);
      const float q = __expf(m1w - m1);      // lane-local (per n) wave correction
      ps = q / zz1;                          // prob scale: pv = e1 * ps
      fh = q * q * cp / zz2;                 // phase-C slice correction
    }

    // ---- phase C: own s-slice, B-frag via in-wave shfl ----
#pragma unroll
    for (int h = 0; h < 2; ++h) {
      const int w0a = __shfl(ew0[2 * h], srcLo),  w0b = __shfl(ew0[2 * h + 1], srcLo);
      const int w1a = __shfl(ew1[2 * h], srcLo),  w1b = __shfl(ew1[2 * h + 1], srcLo);
      const int w2a = __shfl(ew0[2 * h], srcHi),  w2b = __shfl(ew0[2 * h + 1], srcHi);
      const int w3a = __shfl(ew1[2 * h], srcHi),  w3b = __shfl(ew1[2 * h + 1], srcHi);
      union { int w[4]; short8 v; } bfv;
      bfv.w[0] = selHi ? w0b : w0a;
      bfv.w[1] = selHi ? w1b : w1a;
      bfv.w[2] = selHi ? w2b : w2a;
      bfv.w[3] = selHi ? w3b : w3a;
      // A-frag: s-slice [wave*64 + h*32, +32) -> image index hh=wave>>2, widx=(wave&3)*2+h
      const char* afb = b2 + (((wave >> 2) * 8 + (wave & 3) * 2 + h) * 4) * 1024 + lane * 16;
      f32x4 cacc[4] = {{0,0,0,0},{0,0,0,0},{0,0,0,0},{0,0,0,0}};
#pragma unroll
      for (int m = 0; m < 4; ++m) {
        const short8 af = *(const short8*)(afb + m * 1024);
        cacc[m] = __builtin_amdgcn_mfma_f32_16x16x32_bf16(af, bfv.v, cacc[m], 0, 0, 0);
      }
#pragma unroll
      for (int m = 0; m < 4; ++m)
#pragma unroll
        for (int r = 0; r < 4; ++r) zacc[m][r] = fmaf(cacc[m][r], fh, zacc[m][r]);
    }

    // ---- prob/log_prob stores (pv = e1*ps, no extra exp) ----
    float* pp = d_out + 524289 + gb;
    float* pl = pp + 67108864;
#pragma unroll
    for (int i = 0; i < 4; ++i) {
      f32x4 pv, lpv;
#pragma unroll
      for (int r = 0; r < 4; ++r) {
        pv[r]  = e1v[i][r] * ps;
        lpv[r] = lv[i][r] - c1;
      }
      *(f32x4*)(pp + i * 16) = pv;
      *(f32x4*)(pl + i * 16) = lpv;
    }
  }

  // ---- zq cross-wave reduce + partial write ----
  __syncthreads();
#pragma unroll
  for (int m = 0; m < 4; ++m)
    *(f32x4*)(lds + wave * 4096 + l15 * 256 + m * 64 + g4 * 16) = zacc[m];
  __syncthreads();
  const int e = tid * 2;
  f32x2 acc = {0.f, 0.f};
#pragma unroll
  for (int w = 0; w < 8; ++w) acc += *(const f32x2*)(lds + w * 4096 + e * 4);
  *(f32x2*)(ws + WS_ZQP + (unsigned)kg * (1u << 21) +
            (((unsigned)(b * 1024 + n0)) * 64 + e) * 4) = acc;
}

extern "C" void kernel_launch(void* const* d_in, const int* in_sizes, int n_in,
                              void* d_out, int out_size, void* d_ws, size_t ws_size,
                              hipStream_t stream) {
  (void)in_sizes; (void)n_in; (void)out_size; (void)ws_size;
  const float* ze     = (const float*)d_in[0];
  const float* cprobs = (const float*)d_in[1];
  const float* books  = (const float*)d_in[2];
  const float* lpq    = (const float*)d_in[3];
  const float* gum    = (const float*)d_in[4];
  float* out = (float*)d_out;
  char* ws = (char*)d_ws;
  hipLaunchKernelGGL(prep_ze_k,    dim3(32),   dim3(256), 0, stream, ze, ws);
  hipLaunchKernelGGL(prep_bnorm_k, dim3(32),   dim3(256), 0, stream, books, lpq, ws, out);
  hipLaunchKernelGGL(prep_b1_k,    dim3(256),  dim3(256), 0, stream, books, ws);
  hipLaunchKernelGGL(prep_b2_k,    dim3(256),  dim3(256), 0, stream, books, ws);
  hipLaunchKernelGGL(gvq_main,     dim3(1024), dim3(512), 0, stream, gum, cprobs, lpq, ws, out);
  hipLaunchKernelGGL(zq_red_k,     dim3(512),  dim3(256), 0, stream, ws, out);
}

// Round 14
// 297.296 us; speedup vs baseline: 1.1833x; 1.1833x over previous
//
#include <hip/hip_runtime.h>
#include <hip/hip_bf16.h>

typedef __attribute__((ext_vector_type(8))) short short8;
typedef __attribute__((ext_vector_type(4))) float f32x4;
typedef __attribute__((ext_vector_type(2))) float f32x2;

// ---- workspace layout (bytes) ----
#define WS_ZE     0u
#define WS_ZELO   (1u<<20)
#define WS_B1H    (2u<<20)
#define WS_B1L    (3u<<20)
#define WS_B2     (4u<<20)
#define WS_ZN2    (5u<<20)
#define WS_BS2    ((5u<<20)+32768u)
#define WS_ZQP    (6u<<20)

__device__ __forceinline__ unsigned short f2bf(float x) {
  __hip_bfloat16 h = __float2bfloat16(x);
  return __builtin_bit_cast(unsigned short, h);
}
__device__ __forceinline__ float bf2f(unsigned short u) {
  union { unsigned int i; float f; } x; x.i = ((unsigned int)u) << 16; return x.f;
}
// LDS-only barrier: does NOT drain vmcnt -> global stores stay in flight
__device__ __forceinline__ void lds_barrier() {
  asm volatile("s_waitcnt lgkmcnt(0)" ::: "memory");
  __builtin_amdgcn_s_barrier();
}

// ---------------- prep: ze -> bf16 hi/lo + row norms ----------------
__global__ __launch_bounds__(256) void prep_ze_k(const float* __restrict__ ze,
                                                 char* __restrict__ ws) {
  int t = blockIdx.x * 256 + threadIdx.x;
  if (t >= 8 * 1024) return;
  const f32x4* row = (const f32x4*)(ze + t * 64);
  unsigned short* dh = (unsigned short*)(ws + WS_ZE) + t * 64;
  unsigned short* dl = (unsigned short*)(ws + WS_ZELO) + t * 64;
  float s = 0.f;
#pragma unroll
  for (int c = 0; c < 8; ++c) {
    const f32x4 v0 = row[2 * c], v1 = row[2 * c + 1];
    union { unsigned short u[8]; short8 v; } H, L;
#pragma unroll
    for (int r = 0; r < 4; ++r) {
      float a = v0[r]; s += a * a;
      unsigned short h = f2bf(a); H.u[r] = h; L.u[r] = f2bf(a - bf2f(h));
      float b = v1[r]; s += b * b;
      unsigned short h2 = f2bf(b); H.u[4 + r] = h2; L.u[4 + r] = f2bf(b - bf2f(h2));
    }
    *(short8*)(dh + c * 8) = H.v;
    *(short8*)(dl + c * 8) = L.v;
  }
  ((float*)(ws + WS_ZN2))[t] = s;
}

// ---------------- prep: book norms + precision ----------------
__global__ __launch_bounds__(256) void prep_bnorm_k(const float* __restrict__ books,
                                                    const float* __restrict__ lpq,
                                                    char* __restrict__ ws,
                                                    float* __restrict__ d_out) {
  int t = blockIdx.x * 256 + threadIdx.x;
  if (t == 0) d_out[524288] = 0.5f / fmaxf(expf(lpq[0]), 1e-10f);
  if (t >= 16 * 512) return;
  const f32x4* row = (const f32x4*)(books + t * 64);
  float s = 0.f;
#pragma unroll
  for (int c = 0; c < 16; ++c) {
    const f32x4 v = row[c];
#pragma unroll
    for (int r = 0; r < 4; ++r) s += v[r] * v[r];
  }
  ((float*)(ws + WS_BS2))[t] = s;
}

// ---------------- prep: matmul1 A-frag images ----------------
__global__ __launch_bounds__(256) void prep_b1_k(const float* __restrict__ books,
                                                 char* __restrict__ ws) {
  int t = blockIdx.x * 256 + threadIdx.x;
  const int sl = t & 15, g = (t >> 4) & 3, f = (t >> 6) & 1, tt = (t >> 7) & 31, k = t >> 12;
  const float* src = books + ((k * 512 + tt * 16 + sl) * 64 + f * 32 + g * 8);
  const f32x4 v0 = *(const f32x4*)(src);
  const f32x4 v1 = *(const f32x4*)(src + 4);
  union { unsigned short u[8]; short8 v; } H, L;
#pragma unroll
  for (int r = 0; r < 4; ++r) {
    unsigned short h = f2bf(v0[r]); H.u[r] = h; L.u[r] = f2bf(v0[r] - bf2f(h));
    unsigned short h2 = f2bf(v1[r]); H.u[4 + r] = h2; L.u[4 + r] = f2bf(v1[r] - bf2f(h2));
  }
  const int off = (k * 32 + tt) * 2048 + f * 1024 + (sl + g * 16) * 16;
  *(short8*)(ws + WS_B1H + off) = H.v;
  *(short8*)(ws + WS_B1L + off) = L.v;
}

// ---------------- prep: matmul2 A-frag image ----------------
__global__ __launch_bounds__(256) void prep_b2_k(const float* __restrict__ books,
                                                 char* __restrict__ ws) {
  int t = blockIdx.x * 256 + threadIdx.x;
  const int l15 = t & 15, sub = (t >> 4) & 3, m = (t >> 6) & 3, w = (t >> 8) & 7,
            hh = (t >> 11) & 1, k = t >> 12;
  const float* src = books + ((k * 512 + hh * 256 + w * 32 + sub * 8) * 64 + m * 16 + l15);
  union { unsigned short u[8]; short8 v; } H;
#pragma unroll
  for (int j = 0; j < 8; ++j) H.u[j] = f2bf(src[j * 64]);
  *(short8*)(ws + WS_B2 + k * 65536 + ((hh * 8 + w) * 4 + m) * 1024 + (l15 + sub * 16) * 16) = H.v;
}

// ---------------- zq partial reduce ----------------
__global__ __launch_bounds__(256) void zq_red_k(const char* __restrict__ ws,
                                                float* __restrict__ d_out) {
  int t = blockIdx.x * 256 + threadIdx.x;
  const f32x4 a = *(const f32x4*)(ws + WS_ZQP + t * 16);
  const f32x4 b = *(const f32x4*)(ws + WS_ZQP + (1u << 21) + t * 16);
  *(f32x4*)(d_out + t * 4) = a + b;
}

// ---------------- main: LDS-transposed coalesced streaming ----------------
// LDS: logits f32 [16][516] (2064B rows) + enc bf16 [16][520] (1040B rows) = 49664 B
__global__ __launch_bounds__(512, 2)
void gvq_main(const float* __restrict__ gum, const float* __restrict__ cprobs,
              const float* __restrict__ lpq, char* __restrict__ ws,
              float* __restrict__ d_out) {
  __shared__ char lds[49664];
  char* lgb  = lds;            // logits tile
  char* encb = lds + 33024;    // enc tile

  const int tid  = threadIdx.x;
  const int lane = tid & 63;
  const int wave = tid >> 6;
  const int l15  = lane & 15;
  const int g4   = lane >> 4;

  const int bid = blockIdx.x;      // 1024 blocks
  const int kg  = bid & 1;
  const int bt  = bid >> 1;
  const int b   = bt >> 6;
  const int n0  = (bt & 63) * 16;

  const float prec  = 0.5f / fmaxf(expf(lpq[0]), 1e-10f);
  const float prec2 = 2.0f * prec;
  const float C24   = 3.7751345442790977e-11f;   // exp(-24)

  const unsigned short* zh = (const unsigned short*)(ws + WS_ZE)   + (b * 1024 + n0 + l15) * 64;
  const unsigned short* zl = (const unsigned short*)(ws + WS_ZELO) + (b * 1024 + n0 + l15) * 64;
  const short8 zf0h = *(const short8*)(zh + g4 * 8);
  const short8 zf1h = *(const short8*)(zh + 32 + g4 * 8);
  const short8 zf0l = *(const short8*)(zl + g4 * 8);
  const short8 zf1l = *(const short8*)(zl + 32 + g4 * 8);
  const float zn2p = ((const float*)(ws + WS_ZN2))[b * 1024 + n0 + l15] * prec;

  f32x4 zacc[4] = {{0,0,0,0},{0,0,0,0},{0,0,0,0},{0,0,0,0}};

  // phase-B rows owned by this wave (full 512-s rows, s = lane*8..+8)
  const int nr0 = wave * 2, nr1 = wave * 2 + 1;
  const long rb0base = ((long)(b * 16) * 1024 + n0 + nr0) * 512 + lane * 8;
  const long rb1base = ((long)(b * 16) * 1024 + n0 + nr1) * 512 + lane * 8;

#pragma unroll 1
  for (int kk = 0; kk < 8; ++kk) {
    const int k = kg * 8 + kk;
    const float cp = cprobs[b * 16 + k];
    const char* b1h = ws + WS_B1H + k * 65536;
    const char* b1l = ws + WS_B1L + k * 65536;
    const char* b2  = ws + WS_B2  + k * 65536;
    const float* bs2k = (const float*)(ws + WS_BS2) + k * 512;
    const long rb0 = rb0base + (long)k * 524288;
    const long rb1 = rb1base + (long)k * 524288;

    // ---- gumbel prefetch (coalesced 1KB/instr; consumed after barrier1) ----
    const f32x4 u00 = *(const f32x4*)(gum + rb0);
    const f32x4 u01 = *(const f32x4*)(gum + rb0 + 4);
    const f32x4 u10 = *(const f32x4*)(gum + rb1);
    const f32x4 u11 = *(const f32x4*)(gum + rb1 + 4);

    // ---- phase A: logits -> LDS tile (padded rows) ----
#pragma unroll
    for (int i = 0; i < 4; ++i) {
      const int t = wave * 4 + i;
      const char* bh = b1h + t * 2048 + lane * 16;
      const char* bl = b1l + t * 2048 + lane * 16;
      const short8 a0h = *(const short8*)(bh);
      const short8 a1h = *(const short8*)(bh + 1024);
      const short8 a0l = *(const short8*)(bl);
      const short8 a1l = *(const short8*)(bl + 1024);
      f32x4 c = {0.f, 0.f, 0.f, 0.f};
      c = __builtin_amdgcn_mfma_f32_16x16x32_bf16(a0h, zf0h, c, 0, 0, 0);
      c = __builtin_amdgcn_mfma_f32_16x16x32_bf16(a1h, zf1h, c, 0, 0, 0);
      c = __builtin_amdgcn_mfma_f32_16x16x32_bf16(a0h, zf0l, c, 0, 0, 0);
      c = __builtin_amdgcn_mfma_f32_16x16x32_bf16(a1h, zf1l, c, 0, 0, 0);
      c = __builtin_amdgcn_mfma_f32_16x16x32_bf16(a0l, zf0h, c, 0, 0, 0);
      c = __builtin_amdgcn_mfma_f32_16x16x32_bf16(a1l, zf1h, c, 0, 0, 0);
      const f32x4 bs2v = *(const f32x4*)(bs2k + t * 16 + g4 * 4);
      f32x4 lv;
#pragma unroll
      for (int r = 0; r < 4; ++r)
        lv[r] = fmaf(c[r], prec2, fmaf(bs2v[r], -prec, -zn2p));
      // D: col n=l15, rows s=t*16+g4*4+r -> logits[n][s]
      *(f32x4*)(lgb + l15 * 2064 + (t * 16 + g4 * 4) * 4) = lv;
    }
    lds_barrier();                      // barrier 1: logits ready

    // ---- phase B: 2 full rows per wave; all streams coalesced ----
#pragma unroll
    for (int r = 0; r < 2; ++r) {
      const int n = r ? nr1 : nr0;
      const long rb = r ? rb1 : rb0;
      const f32x4 U0 = r ? u10 : u00;
      const f32x4 U1 = r ? u11 : u01;
      const char* lrow = lgb + n * 2064 + lane * 32;
      const f32x4 L0 = *(const f32x4*)(lrow);
      const f32x4 L1 = *(const f32x4*)(lrow + 16);

      // full-row max (in-wave)
      float m = fmaxf(fmaxf(fmaxf(L0[0], L0[1]), fmaxf(L0[2], L0[3])),
                      fmaxf(fmaxf(L1[0], L1[1]), fmaxf(L1[2], L1[3])));
#pragma unroll
      for (int o = 1; o < 64; o <<= 1) m = fmaxf(m, __shfl_xor(m, o));

      // e1, e2 (bound-max: m2 = 2m+24)
      f32x4 e10, e11, t0, t1;
      float z1 = 0.f, z2 = 0.f;
#pragma unroll
      for (int j = 0; j < 4; ++j) {
        e10[j] = __expf(L0[j] - m); z1 += e10[j];
        e11[j] = __expf(L1[j] - m); z1 += e11[j];
        const float La = 1e-10f - __logf(U0[j] + 1e-10f);
        const float ra = __builtin_amdgcn_rcpf(La);
        t0[j] = (e10[j] * e10[j]) * (ra * ra) * C24; z2 += t0[j];
        const float Lb = 1e-10f - __logf(U1[j] + 1e-10f);
        const float rbq = __builtin_amdgcn_rcpf(Lb);
        t1[j] = (e11[j] * e11[j]) * (rbq * rbq) * C24; z2 += t1[j];
      }
#pragma unroll
      for (int o = 1; o < 64; o <<= 1) {
        z1 += __shfl_xor(z1, o);
        z2 += __shfl_xor(z2, o);
      }
      const float rz1 = 1.0f / z1;
      const float c1  = m + __logf(z1);
      const float esc = cp / z2;         // fold c_probs + normalization into enc

      // enc row write (16B/lane, padded row)
      union { unsigned short u[8]; short8 v; } ew;
#pragma unroll
      for (int j = 0; j < 4; ++j) {
        ew.u[j]     = f2bf(t0[j] * esc);
        ew.u[4 + j] = f2bf(t1[j] * esc);
      }
      *(short8*)(encb + n * 1040 + lane * 16) = ew.v;

      // coalesced prob/log_prob stores (1KB/instr per wave)
      float* pp = d_out + 524289 + rb;
      float* pl = pp + 67108864;
      f32x4 pv0, pv1, lp0, lp1;
#pragma unroll
      for (int j = 0; j < 4; ++j) {
        pv0[j] = e10[j] * rz1;  lp0[j] = L0[j] - c1;
        pv1[j] = e11[j] * rz1;  lp1[j] = L1[j] - c1;
      }
      *(f32x4*)(pp)     = pv0;
      *(f32x4*)(pp + 4) = pv1;
      *(f32x4*)(pl)     = lp0;
      *(f32x4*)(pl + 4) = lp1;
    }
    lds_barrier();                      // barrier 2: enc ready

    // ---- phase C: zacc += booksT . encT (enc pre-scaled; direct accumulate) ----
#pragma unroll
    for (int h = 0; h < 2; ++h) {
      const short8 bf = *(const short8*)(encb + l15 * 1040 +
                                         (h * 256 + wave * 32 + g4 * 8) * 2);
      const char* afb = b2 + ((h * 8 + wave) * 4) * 1024 + lane * 16;
#pragma unroll
      for (int m = 0; m < 4; ++m) {
        const short8 af = *(const short8*)(afb + m * 1024);
        zacc[m] = __builtin_amdgcn_mfma_f32_16x16x32_bf16(af, bf, zacc[m], 0, 0, 0);
      }
    }
  }

  // ---- zq cross-wave reduce + partial write ----
  __syncthreads();
#pragma unroll
  for (int m = 0; m < 4; ++m)
    *(f32x4*)(lds + wave * 4096 + l15 * 256 + m * 64 + g4 * 16) = zacc[m];
  __syncthreads();
  const int e = tid * 2;
  f32x2 acc = {0.f, 0.f};
#pragma unroll
  for (int w = 0; w < 8; ++w) acc += *(const f32x2*)(lds + w * 4096 + e * 4);
  *(f32x2*)(ws + WS_ZQP + (unsigned)kg * (1u << 21) +
            (((unsigned)(b * 1024 + n0)) * 64 + e) * 4) = acc;
}

extern "C" void kernel_launch(void* const* d_in, const int* in_sizes, int n_in,
                              void* d_out, int out_size, void* d_ws, size_t ws_size,
                              hipStream_t stream) {
  (void)in_sizes; (void)n_in; (void)out_size; (void)ws_size;
  const float* ze     = (const float*)d_in[0];
  const float* cprobs = (const float*)d_in[1];
  const float* books  = (const float*)d_in[2];
  const float* lpq    = (const float*)d_in[3];
  const float* gum    = (const float*)d_in[4];
  float* out = (float*)d_out;
  char* ws = (char*)d_ws;
  hipLaunchKernelGGL(prep_ze_k,    dim3(32),   dim3(256), 0, stream, ze, ws);
  hipLaunchKernelGGL(prep_bnorm_k, dim3(32),   dim3(256), 0, stream, books, lpq, ws, out);
  hipLaunchKernelGGL(prep_b1_k,    dim3(256),  dim3(256), 0, stream, books, ws);
  hipLaunchKernelGGL(prep_b2_k,    dim3(256),  dim3(256), 0, stream, books, ws);
  hipLaunchKernelGGL(gvq_main,     dim3(1024), dim3(512), 0, stream, gum, cprobs, lpq, ws, out);
  hipLaunchKernelGGL(zq_red_k,     dim3(512),  dim3(256), 0, stream, ws, out);
}

// Round 15
// 253.874 us; speedup vs baseline: 1.3857x; 1.1710x over previous
//
#include <hip/hip_runtime.h>
#include <hip/hip_bf16.h>

typedef __attribute__((ext_vector_type(8))) short short8;
typedef __attribute__((ext_vector_type(4))) float f32x4;
typedef __attribute__((ext_vector_type(2))) float f32x2;

// ---- workspace layout (bytes) ----
#define WS_ZE     0u
#define WS_ZELO   (1u<<20)
#define WS_B1H    (2u<<20)
#define WS_B1L    (3u<<20)
#define WS_B2     (4u<<20)
#define WS_ZN2    (5u<<20)
#define WS_BS2    ((5u<<20)+32768u)
#define WS_ZQP    (6u<<20)

__device__ __forceinline__ unsigned short f2bf(float x) {
  __hip_bfloat16 h = __float2bfloat16(x);
  return __builtin_bit_cast(unsigned short, h);
}
__device__ __forceinline__ float bf2f(unsigned short u) {
  union { unsigned int i; float f; } x; x.i = ((unsigned int)u) << 16; return x.f;
}
// LDS-only barrier: does NOT drain vmcnt -> global stores stay in flight
__device__ __forceinline__ void lds_barrier() {
  asm volatile("s_waitcnt lgkmcnt(0)" ::: "memory");
  __builtin_amdgcn_s_barrier();
}

// ---------------- prep: ze -> bf16 hi/lo + row norms ----------------
__global__ __launch_bounds__(256) void prep_ze_k(const float* __restrict__ ze,
                                                 char* __restrict__ ws) {
  int t = blockIdx.x * 256 + threadIdx.x;
  if (t >= 8 * 1024) return;
  const f32x4* row = (const f32x4*)(ze + t * 64);
  unsigned short* dh = (unsigned short*)(ws + WS_ZE) + t * 64;
  unsigned short* dl = (unsigned short*)(ws + WS_ZELO) + t * 64;
  float s = 0.f;
#pragma unroll
  for (int c = 0; c < 8; ++c) {
    const f32x4 v0 = row[2 * c], v1 = row[2 * c + 1];
    union { unsigned short u[8]; short8 v; } H, L;
#pragma unroll
    for (int r = 0; r < 4; ++r) {
      float a = v0[r]; s += a * a;
      unsigned short h = f2bf(a); H.u[r] = h; L.u[r] = f2bf(a - bf2f(h));
      float b = v1[r]; s += b * b;
      unsigned short h2 = f2bf(b); H.u[4 + r] = h2; L.u[4 + r] = f2bf(b - bf2f(h2));
    }
    *(short8*)(dh + c * 8) = H.v;
    *(short8*)(dl + c * 8) = L.v;
  }
  ((float*)(ws + WS_ZN2))[t] = s;
}

// ---------------- prep: book norms + precision ----------------
__global__ __launch_bounds__(256) void prep_bnorm_k(const float* __restrict__ books,
                                                    const float* __restrict__ lpq,
                                                    char* __restrict__ ws,
                                                    float* __restrict__ d_out) {
  int t = blockIdx.x * 256 + threadIdx.x;
  if (t == 0) d_out[524288] = 0.5f / fmaxf(expf(lpq[0]), 1e-10f);
  if (t >= 16 * 512) return;
  const f32x4* row = (const f32x4*)(books + t * 64);
  float s = 0.f;
#pragma unroll
  for (int c = 0; c < 16; ++c) {
    const f32x4 v = row[c];
#pragma unroll
    for (int r = 0; r < 4; ++r) s += v[r] * v[r];
  }
  ((float*)(ws + WS_BS2))[t] = s;
}

// ---------------- prep: matmul1 A-frag images ----------------
__global__ __launch_bounds__(256) void prep_b1_k(const float* __restrict__ books,
                                                 char* __restrict__ ws) {
  int t = blockIdx.x * 256 + threadIdx.x;
  const int sl = t & 15, g = (t >> 4) & 3, f = (t >> 6) & 1, tt = (t >> 7) & 31, k = t >> 12;
  const float* src = books + ((k * 512 + tt * 16 + sl) * 64 + f * 32 + g * 8);
  const f32x4 v0 = *(const f32x4*)(src);
  const f32x4 v1 = *(const f32x4*)(src + 4);
  union { unsigned short u[8]; short8 v; } H, L;
#pragma unroll
  for (int r = 0; r < 4; ++r) {
    unsigned short h = f2bf(v0[r]); H.u[r] = h; L.u[r] = f2bf(v0[r] - bf2f(h));
    unsigned short h2 = f2bf(v1[r]); H.u[4 + r] = h2; L.u[4 + r] = f2bf(v1[r] - bf2f(h2));
  }
  const int off = (k * 32 + tt) * 2048 + f * 1024 + (sl + g * 16) * 16;
  *(short8*)(ws + WS_B1H + off) = H.v;
  *(short8*)(ws + WS_B1L + off) = L.v;
}

// ---------------- prep: matmul2 A-frag image ----------------
__global__ __launch_bounds__(256) void prep_b2_k(const float* __restrict__ books,
                                                 char* __restrict__ ws) {
  int t = blockIdx.x * 256 + threadIdx.x;
  const int l15 = t & 15, sub = (t >> 4) & 3, m = (t >> 6) & 3, w = (t >> 8) & 7,
            hh = (t >> 11) & 1, k = t >> 12;
  const float* src = books + ((k * 512 + hh * 256 + w * 32 + sub * 8) * 64 + m * 16 + l15);
  union { unsigned short u[8]; short8 v; } H;
#pragma unroll
  for (int j = 0; j < 8; ++j) H.u[j] = f2bf(src[j * 64]);
  *(short8*)(ws + WS_B2 + k * 65536 + ((hh * 8 + w) * 4 + m) * 1024 + (l15 + sub * 16) * 16) = H.v;
}

// ---------------- zq partial reduce ----------------
__global__ __launch_bounds__(256) void zq_red_k(const char* __restrict__ ws,
                                                float* __restrict__ d_out) {
  int t = blockIdx.x * 256 + threadIdx.x;
  const f32x4 a = *(const f32x4*)(ws + WS_ZQP + t * 16);
  const f32x4 b = *(const f32x4*)(ws + WS_ZQP + (1u << 21) + t * 16);
  *(f32x4*)(d_out + t * 4) = a + b;
}

// ---------------- main: dword nt-streams (alignment-immune), LDS-transposed ----------------
// LDS: logits f32 [16][516] (2064B rows) + enc bf16 [16][520] (1040B rows) = 49664 B
__global__ __launch_bounds__(512, 2)
void gvq_main(const float* __restrict__ gum, const float* __restrict__ cprobs,
              const float* __restrict__ lpq, char* __restrict__ ws,
              float* __restrict__ d_out) {
  __shared__ char lds[49664];
  char* lgb  = lds;            // logits tile
  char* encb = lds + 33024;    // enc tile

  const int tid  = threadIdx.x;
  const int lane = tid & 63;
  const int wave = tid >> 6;
  const int l15  = lane & 15;
  const int g4   = lane >> 4;

  const int bid = blockIdx.x;      // 1024 blocks
  const int kg  = bid & 1;
  const int bt  = bid >> 1;
  const int b   = bt >> 6;
  const int n0  = (bt & 63) * 16;

  const float prec  = 0.5f / fmaxf(expf(lpq[0]), 1e-10f);
  const float prec2 = 2.0f * prec;
  const float C24   = 3.7751345442790977e-11f;   // exp(-24)

  const unsigned short* zh = (const unsigned short*)(ws + WS_ZE)   + (b * 1024 + n0 + l15) * 64;
  const unsigned short* zl = (const unsigned short*)(ws + WS_ZELO) + (b * 1024 + n0 + l15) * 64;
  const short8 zf0h = *(const short8*)(zh + g4 * 8);
  const short8 zf1h = *(const short8*)(zh + 32 + g4 * 8);
  const short8 zf0l = *(const short8*)(zl + g4 * 8);
  const short8 zf1l = *(const short8*)(zl + 32 + g4 * 8);
  const float zn2p = ((const float*)(ws + WS_ZN2))[b * 1024 + n0 + l15] * prec;

  f32x4 zacc[4] = {{0,0,0,0},{0,0,0,0},{0,0,0,0},{0,0,0,0}};

  const int nr0 = wave * 2, nr1 = wave * 2 + 1;

#pragma unroll 1
  for (int kk = 0; kk < 8; ++kk) {
    const int k = kg * 8 + kk;
    const float cp = cprobs[b * 16 + k];
    const char* b1h = ws + WS_B1H + k * 65536;
    const char* b1l = ws + WS_B1L + k * 65536;
    const char* b2  = ws + WS_B2  + k * 65536;
    const float* bs2k = (const float*)(ws + WS_BS2) + k * 512;
    const long row0 = ((long)((b * 16 + k) * 1024) + n0 + nr0) * 512;
    const long row1 = ((long)((b * 16 + k) * 1024) + n0 + nr1) * 512;

    // ---- gumbel prefetch: dword, wave-contiguous, non-temporal ----
    float uv0[8], uv1[8];
#pragma unroll
    for (int j = 0; j < 8; ++j)
      uv0[j] = __builtin_nontemporal_load(gum + row0 + j * 64 + lane);
#pragma unroll
    for (int j = 0; j < 8; ++j)
      uv1[j] = __builtin_nontemporal_load(gum + row1 + j * 64 + lane);

    // ---- phase A: logits -> LDS tile (padded rows) ----
#pragma unroll
    for (int i = 0; i < 4; ++i) {
      const int t = wave * 4 + i;
      const char* bh = b1h + t * 2048 + lane * 16;
      const char* bl = b1l + t * 2048 + lane * 16;
      const short8 a0h = *(const short8*)(bh);
      const short8 a1h = *(const short8*)(bh + 1024);
      const short8 a0l = *(const short8*)(bl);
      const short8 a1l = *(const short8*)(bl + 1024);
      f32x4 c = {0.f, 0.f, 0.f, 0.f};
      c = __builtin_amdgcn_mfma_f32_16x16x32_bf16(a0h, zf0h, c, 0, 0, 0);
      c = __builtin_amdgcn_mfma_f32_16x16x32_bf16(a1h, zf1h, c, 0, 0, 0);
      c = __builtin_amdgcn_mfma_f32_16x16x32_bf16(a0h, zf0l, c, 0, 0, 0);
      c = __builtin_amdgcn_mfma_f32_16x16x32_bf16(a1h, zf1l, c, 0, 0, 0);
      c = __builtin_amdgcn_mfma_f32_16x16x32_bf16(a0l, zf0h, c, 0, 0, 0);
      c = __builtin_amdgcn_mfma_f32_16x16x32_bf16(a1l, zf1h, c, 0, 0, 0);
      const f32x4 bs2v = *(const f32x4*)(bs2k + t * 16 + g4 * 4);
      f32x4 lv;
#pragma unroll
      for (int r = 0; r < 4; ++r)
        lv[r] = fmaf(c[r], prec2, fmaf(bs2v[r], -prec, -zn2p));
      *(f32x4*)(lgb + l15 * 2064 + (t * 16 + g4 * 4) * 4) = lv;
    }
    lds_barrier();                      // barrier 1: logits ready

    // ---- phase B: 2 full rows per wave; all streams dword-coalesced ----
#pragma unroll
    for (int r = 0; r < 2; ++r) {
      const int n = r ? nr1 : nr0;
      const long rowb = r ? row1 : row0;
      float Lv[8], e1[8], tv[8];
      const float* l32 = (const float*)(lgb + n * 2064);
#pragma unroll
      for (int j = 0; j < 8; ++j) Lv[j] = l32[j * 64 + lane];

      // full-row max
      float m = Lv[0];
#pragma unroll
      for (int j = 1; j < 8; ++j) m = fmaxf(m, Lv[j]);
#pragma unroll
      for (int o = 1; o < 64; o <<= 1) m = fmaxf(m, __shfl_xor(m, o));

      // e1, e2 (bound-max: m2 = 2m+24)
      float z1 = 0.f, z2 = 0.f;
#pragma unroll
      for (int j = 0; j < 8; ++j) {
        const float u = r ? uv1[j] : uv0[j];
        e1[j] = __expf(Lv[j] - m); z1 += e1[j];
        const float L  = 1e-10f - __logf(u + 1e-10f);
        const float rl = __builtin_amdgcn_rcpf(L);
        tv[j] = (e1[j] * e1[j]) * (rl * rl) * C24; z2 += tv[j];
      }
#pragma unroll
      for (int o = 1; o < 64; o <<= 1) {
        z1 += __shfl_xor(z1, o);
        z2 += __shfl_xor(z2, o);
      }
      const float rz1 = 1.0f / z1;
      const float c1  = m + __logf(z1);
      const float esc = cp / z2;         // fold c_probs + normalization into enc

      // enc row write (b16, 2 lanes/bank - free)
      unsigned short* er = (unsigned short*)(encb + n * 1040);
#pragma unroll
      for (int j = 0; j < 8; ++j) er[j * 64 + lane] = f2bf(tv[j] * esc);

      // dword nt-stores: wave-contiguous 256B, alignment-immune
      float* pp = d_out + 524289 + rowb;
      float* pl = pp + 67108864;
#pragma unroll
      for (int j = 0; j < 8; ++j)
        __builtin_nontemporal_store(e1[j] * rz1, pp + j * 64 + lane);
#pragma unroll
      for (int j = 0; j < 8; ++j)
        __builtin_nontemporal_store(Lv[j] - c1, pl + j * 64 + lane);
    }
    lds_barrier();                      // barrier 2: enc ready

    // ---- phase C: zacc += booksT . encT (enc pre-scaled) ----
#pragma unroll
    for (int h = 0; h < 2; ++h) {
      const short8 bf = *(const short8*)(encb + l15 * 1040 +
                                         (h * 256 + wave * 32 + g4 * 8) * 2);
      const char* afb = b2 + ((h * 8 + wave) * 4) * 1024 + lane * 16;
#pragma unroll
      for (int m = 0; m < 4; ++m) {
        const short8 af = *(const short8*)(afb + m * 1024);
        zacc[m] = __builtin_amdgcn_mfma_f32_16x16x32_bf16(af, bf, zacc[m], 0, 0, 0);
      }
    }
  }

  // ---- zq cross-wave reduce + partial write ----
  __syncthreads();
#pragma unroll
  for (int m = 0; m < 4; ++m)
    *(f32x4*)(lds + wave * 4096 + l15 * 256 + m * 64 + g4 * 16) = zacc[m];
  __syncthreads();
  const int e = tid * 2;
  f32x2 acc = {0.f, 0.f};
#pragma unroll
  for (int w = 0; w < 8; ++w) acc += *(const f32x2*)(lds + w * 4096 + e * 4);
  *(f32x2*)(ws + WS_ZQP + (unsigned)kg * (1u << 21) +
            (((unsigned)(b * 1024 + n0)) * 64 + e) * 4) = acc;
}

extern "C" void kernel_launch(void* const* d_in, const int* in_sizes, int n_in,
                              void* d_out, int out_size, void* d_ws, size_t ws_size,
                              hipStream_t stream) {
  (void)in_sizes; (void)n_in; (void)out_size; (void)ws_size;
  const float* ze     = (const float*)d_in[0];
  const float* cprobs = (const float*)d_in[1];
  const float* books  = (const float*)d_in[2];
  const float* lpq    = (const float*)d_in[3];
  const float* gum    = (const float*)d_in[4];
  float* out = (float*)d_out;
  char* ws = (char*)d_ws;
  hipLaunchKernelGGL(prep_ze_k,    dim3(32),   dim3(256), 0, stream, ze, ws);
  hipLaunchKernelGGL(prep_bnorm_k, dim3(32),   dim3(256), 0, stream, books, lpq, ws, out);
  hipLaunchKernelGGL(prep_b1_k,    dim3(256),  dim3(256), 0, stream, books, ws);
  hipLaunchKernelGGL(prep_b2_k,    dim3(256),  dim3(256), 0, stream, books, ws);
  hipLaunchKernelGGL(gvq_main,     dim3(1024), dim3(512), 0, stream, gum, cprobs, lpq, ws, out);
  hipLaunchKernelGGL(zq_red_k,     dim3(512),  dim3(256), 0, stream, ws, out);
}

// Round 16
// 236.699 us; speedup vs baseline: 1.4862x; 1.0726x over previous
//
#include <hip/hip_runtime.h>
#include <hip/hip_bf16.h>

typedef __attribute__((ext_vector_type(8))) short short8;
typedef __attribute__((ext_vector_type(4))) float f32x4;
typedef __attribute__((ext_vector_type(2))) float f32x2;

// ---- workspace layout (bytes) ----
#define WS_ZE     0u
#define WS_ZELO   (1u<<20)
#define WS_B1H    (2u<<20)
#define WS_B1L    (3u<<20)
#define WS_B2     (4u<<20)
#define WS_ZN2    (5u<<20)
#define WS_BS2    ((5u<<20)+32768u)
#define WS_ZQP    (6u<<20)

__device__ __forceinline__ unsigned short f2bf(float x) {
  __hip_bfloat16 h = __float2bfloat16(x);
  return __builtin_bit_cast(unsigned short, h);
}
__device__ __forceinline__ float bf2f(unsigned short u) {
  union { unsigned int i; float f; } x; x.i = ((unsigned int)u) << 16; return x.f;
}
// LDS-only barrier: does NOT drain vmcnt -> global stores stay in flight
__device__ __forceinline__ void lds_barrier() {
  asm volatile("s_waitcnt lgkmcnt(0)" ::: "memory");
  __builtin_amdgcn_s_barrier();
}

// ---------------- prep: ze -> bf16 hi/lo + row norms ----------------
__global__ __launch_bounds__(256) void prep_ze_k(const float* __restrict__ ze,
                                                 char* __restrict__ ws) {
  int t = blockIdx.x * 256 + threadIdx.x;
  if (t >= 8 * 1024) return;
  const f32x4* row = (const f32x4*)(ze + t * 64);
  unsigned short* dh = (unsigned short*)(ws + WS_ZE) + t * 64;
  unsigned short* dl = (unsigned short*)(ws + WS_ZELO) + t * 64;
  float s = 0.f;
#pragma unroll
  for (int c = 0; c < 8; ++c) {
    const f32x4 v0 = row[2 * c], v1 = row[2 * c + 1];
    union { unsigned short u[8]; short8 v; } H, L;
#pragma unroll
    for (int r = 0; r < 4; ++r) {
      float a = v0[r]; s += a * a;
      unsigned short h = f2bf(a); H.u[r] = h; L.u[r] = f2bf(a - bf2f(h));
      float b = v1[r]; s += b * b;
      unsigned short h2 = f2bf(b); H.u[4 + r] = h2; L.u[4 + r] = f2bf(b - bf2f(h2));
    }
    *(short8*)(dh + c * 8) = H.v;
    *(short8*)(dl + c * 8) = L.v;
  }
  ((float*)(ws + WS_ZN2))[t] = s;
}

// ---------------- prep: book norms + precision ----------------
__global__ __launch_bounds__(256) void prep_bnorm_k(const float* __restrict__ books,
                                                    const float* __restrict__ lpq,
                                                    char* __restrict__ ws,
                                                    float* __restrict__ d_out) {
  int t = blockIdx.x * 256 + threadIdx.x;
  if (t == 0) d_out[524288] = 0.5f / fmaxf(expf(lpq[0]), 1e-10f);
  if (t >= 16 * 512) return;
  const f32x4* row = (const f32x4*)(books + t * 64);
  float s = 0.f;
#pragma unroll
  for (int c = 0; c < 16; ++c) {
    const f32x4 v = row[c];
#pragma unroll
    for (int r = 0; r < 4; ++r) s += v[r] * v[r];
  }
  ((float*)(ws + WS_BS2))[t] = s;
}

// ---------------- prep: matmul1 A-frag images ----------------
__global__ __launch_bounds__(256) void prep_b1_k(const float* __restrict__ books,
                                                 char* __restrict__ ws) {
  int t = blockIdx.x * 256 + threadIdx.x;
  const int sl = t & 15, g = (t >> 4) & 3, f = (t >> 6) & 1, tt = (t >> 7) & 31, k = t >> 12;
  const float* src = books + ((k * 512 + tt * 16 + sl) * 64 + f * 32 + g * 8);
  const f32x4 v0 = *(const f32x4*)(src);
  const f32x4 v1 = *(const f32x4*)(src + 4);
  union { unsigned short u[8]; short8 v; } H, L;
#pragma unroll
  for (int r = 0; r < 4; ++r) {
    unsigned short h = f2bf(v0[r]); H.u[r] = h; L.u[r] = f2bf(v0[r] - bf2f(h));
    unsigned short h2 = f2bf(v1[r]); H.u[4 + r] = h2; L.u[4 + r] = f2bf(v1[r] - bf2f(h2));
  }
  const int off = (k * 32 + tt) * 2048 + f * 1024 + (sl + g * 16) * 16;
  *(short8*)(ws + WS_B1H + off) = H.v;
  *(short8*)(ws + WS_B1L + off) = L.v;
}

// ---------------- prep: matmul2 A-frag image ----------------
__global__ __launch_bounds__(256) void prep_b2_k(const float* __restrict__ books,
                                                 char* __restrict__ ws) {
  int t = blockIdx.x * 256 + threadIdx.x;
  const int l15 = t & 15, sub = (t >> 4) & 3, m = (t >> 6) & 3, w = (t >> 8) & 7,
            hh = (t >> 11) & 1, k = t >> 12;
  const float* src = books + ((k * 512 + hh * 256 + w * 32 + sub * 8) * 64 + m * 16 + l15);
  union { unsigned short u[8]; short8 v; } H;
#pragma unroll
  for (int j = 0; j < 8; ++j) H.u[j] = f2bf(src[j * 64]);
  *(short8*)(ws + WS_B2 + k * 65536 + ((hh * 8 + w) * 4 + m) * 1024 + (l15 + sub * 16) * 16) = H.v;
}

// ---------------- zq partial reduce ----------------
__global__ __launch_bounds__(256) void zq_red_k(const char* __restrict__ ws,
                                                float* __restrict__ d_out) {
  int t = blockIdx.x * 256 + threadIdx.x;
  const f32x4 a = *(const f32x4*)(ws + WS_ZQP + t * 16);
  const f32x4 b = *(const f32x4*)(ws + WS_ZQP + (1u << 21) + t * 16);
  *(f32x4*)(d_out + t * 4) = a + b;
}

// ---------------- main: 3 blocks/CU, dword nt-streams, lane-local enc scale ----------------
// LDS: logits f32 [16][516] (2064B) = 33024 + enc bf16 [16][536] (1072B) = 17152 + esc 64 = 50240 B
__global__ __launch_bounds__(512, 3)
void gvq_main(const float* __restrict__ gum, const float* __restrict__ cprobs,
              const float* __restrict__ lpq, char* __restrict__ ws,
              float* __restrict__ d_out) {
  __shared__ char lds[50240];
  char* lgb  = lds;                    // logits tile
  char* encb = lds + 33024;            // enc tile (unscaled e2)
  float* scr_esc = (float*)(lds + 50176);  // [16] per-row esc = cp/z2

  const int tid  = threadIdx.x;
  const int lane = tid & 63;
  const int wave = tid >> 6;
  const int l15  = lane & 15;
  const int g4   = lane >> 4;

  const int bid = blockIdx.x;      // 1024 blocks
  const int kg  = bid & 1;
  const int bt  = bid >> 1;
  const int b   = bt >> 6;
  const int n0  = (bt & 63) * 16;

  const float prec  = 0.5f / fmaxf(expf(lpq[0]), 1e-10f);
  const float prec2 = 2.0f * prec;
  const float C24   = 3.7751345442790977e-11f;   // exp(-24)

  const unsigned short* zh = (const unsigned short*)(ws + WS_ZE)   + (b * 1024 + n0 + l15) * 64;
  const unsigned short* zl = (const unsigned short*)(ws + WS_ZELO) + (b * 1024 + n0 + l15) * 64;
  const short8 zf0h = *(const short8*)(zh + g4 * 8);
  const short8 zf1h = *(const short8*)(zh + 32 + g4 * 8);
  const short8 zf0l = *(const short8*)(zl + g4 * 8);
  const short8 zf1l = *(const short8*)(zl + 32 + g4 * 8);
  const float zn2p = ((const float*)(ws + WS_ZN2))[b * 1024 + n0 + l15] * prec;

  f32x4 zacc[4] = {{0,0,0,0},{0,0,0,0},{0,0,0,0},{0,0,0,0}};

  const int nr0 = wave * 2, nr1 = wave * 2 + 1;

#pragma unroll 1
  for (int kk = 0; kk < 8; ++kk) {
    const int k = kg * 8 + kk;
    const float cp = cprobs[b * 16 + k];
    const char* b1h = ws + WS_B1H + k * 65536;
    const char* b1l = ws + WS_B1L + k * 65536;
    const char* b2  = ws + WS_B2  + k * 65536;
    const float* bs2k = (const float*)(ws + WS_BS2) + k * 512;
    const long row0 = ((long)((b * 16 + k) * 1024) + n0 + nr0) * 512;
    const long row1 = ((long)((b * 16 + k) * 1024) + n0 + nr1) * 512;

    // ---- phase A: logits -> LDS tile (padded rows) ----
#pragma unroll
    for (int i = 0; i < 4; ++i) {
      const int t = wave * 4 + i;
      const char* bh = b1h + t * 2048 + lane * 16;
      const char* bl = b1l + t * 2048 + lane * 16;
      const short8 a0h = *(const short8*)(bh);
      const short8 a1h = *(const short8*)(bh + 1024);
      const short8 a0l = *(const short8*)(bl);
      const short8 a1l = *(const short8*)(bl + 1024);
      f32x4 c = {0.f, 0.f, 0.f, 0.f};
      c = __builtin_amdgcn_mfma_f32_16x16x32_bf16(a0h, zf0h, c, 0, 0, 0);
      c = __builtin_amdgcn_mfma_f32_16x16x32_bf16(a1h, zf1h, c, 0, 0, 0);
      c = __builtin_amdgcn_mfma_f32_16x16x32_bf16(a0h, zf0l, c, 0, 0, 0);
      c = __builtin_amdgcn_mfma_f32_16x16x32_bf16(a1h, zf1l, c, 0, 0, 0);
      c = __builtin_amdgcn_mfma_f32_16x16x32_bf16(a0l, zf0h, c, 0, 0, 0);
      c = __builtin_amdgcn_mfma_f32_16x16x32_bf16(a1l, zf1h, c, 0, 0, 0);
      const f32x4 bs2v = *(const f32x4*)(bs2k + t * 16 + g4 * 4);
      f32x4 lv;
#pragma unroll
      for (int r = 0; r < 4; ++r)
        lv[r] = fmaf(c[r], prec2, fmaf(bs2v[r], -prec, -zn2p));
      *(f32x4*)(lgb + l15 * 2064 + (t * 16 + g4 * 4) * 4) = lv;
    }

    // ---- gumbel loads issued here: in flight across barrier + max-reduce ----
    float uv0[8], uv1[8];
#pragma unroll
    for (int j = 0; j < 8; ++j)
      uv0[j] = __builtin_nontemporal_load(gum + row0 + j * 64 + lane);
#pragma unroll
    for (int j = 0; j < 8; ++j)
      uv1[j] = __builtin_nontemporal_load(gum + row1 + j * 64 + lane);

    lds_barrier();                      // barrier 1: logits ready

    // ---- phase B: 2 full rows per wave; all streams dword-coalesced ----
#pragma unroll
    for (int r = 0; r < 2; ++r) {
      const int n = r ? nr1 : nr0;
      const long rowb = r ? row1 : row0;
      float Lv[8], e1[8];
      const float* l32 = (const float*)(lgb + n * 2064);
#pragma unroll
      for (int j = 0; j < 8; ++j) Lv[j] = l32[j * 64 + lane];

      // full-row max
      float m = Lv[0];
#pragma unroll
      for (int j = 1; j < 8; ++j) m = fmaxf(m, Lv[j]);
#pragma unroll
      for (int o = 1; o < 64; o <<= 1) m = fmaxf(m, __shfl_xor(m, o));

      // e1; e2 unscaled (bound-max m2 = 2m+24) packed straight to LDS
      unsigned short* er = (unsigned short*)(encb + n * 1072);
      float z1 = 0.f, z2 = 0.f;
#pragma unroll
      for (int j = 0; j < 8; ++j) {
        const float u = r ? uv1[j] : uv0[j];
        e1[j] = __expf(Lv[j] - m); z1 += e1[j];
        const float L  = 1e-10f - __logf(u + 1e-10f);
        const float rl = __builtin_amdgcn_rcpf(L);
        const float e2 = (e1[j] * e1[j]) * (rl * rl) * C24;
        z2 += e2;
        er[j * 64 + lane] = f2bf(e2);
      }
#pragma unroll
      for (int o = 1; o < 64; o <<= 1) {
        z1 += __shfl_xor(z1, o);
        z2 += __shfl_xor(z2, o);
      }
      const float rz1 = 1.0f / z1;
      const float c1  = m + __logf(z1);
      if (lane == 0) scr_esc[n] = cp / z2;   // per-row enc scale, applied in phase C

      // dword nt-stores: wave-contiguous 256B, alignment-immune
      float* pp = d_out + 524289 + rowb;
      float* pl = pp + 67108864;
#pragma unroll
      for (int j = 0; j < 8; ++j)
        __builtin_nontemporal_store(e1[j] * rz1, pp + j * 64 + lane);
#pragma unroll
      for (int j = 0; j < 8; ++j)
        __builtin_nontemporal_store(Lv[j] - c1, pl + j * 64 + lane);
    }
    lds_barrier();                      // barrier 2: enc + esc ready

    // ---- phase C: cacc = booksT . encT (both h), then zacc += cacc * esc[l15] ----
    {
      f32x4 cacc[4] = {{0,0,0,0},{0,0,0,0},{0,0,0,0},{0,0,0,0}};
#pragma unroll
      for (int h = 0; h < 2; ++h) {
        const short8 bf = *(const short8*)(encb + l15 * 1072 +
                                           (h * 256 + wave * 32 + g4 * 8) * 2);
        const char* afb = b2 + ((h * 8 + wave) * 4) * 1024 + lane * 16;
#pragma unroll
        for (int m = 0; m < 4; ++m) {
          const short8 af = *(const short8*)(afb + m * 1024);
          cacc[m] = __builtin_amdgcn_mfma_f32_16x16x32_bf16(af, bf, cacc[m], 0, 0, 0);
        }
      }
      const float esc = scr_esc[l15];   // output col = l15 = n -> lane-local scale
#pragma unroll
      for (int m = 0; m < 4; ++m)
#pragma unroll
        for (int r = 0; r < 4; ++r) zacc[m][r] = fmaf(cacc[m][r], esc, zacc[m][r]);
    }
  }

  // ---- zq cross-wave reduce + partial write ----
  __syncthreads();
#pragma unroll
  for (int m = 0; m < 4; ++m)
    *(f32x4*)(lds + wave * 4096 + l15 * 256 + m * 64 + g4 * 16) = zacc[m];
  __syncthreads();
  const int e = tid * 2;
  f32x2 acc = {0.f, 0.f};
#pragma unroll
  for (int w = 0; w < 8; ++w) acc += *(const f32x2*)(lds + w * 4096 + e * 4);
  *(f32x2*)(ws + WS_ZQP + (unsigned)kg * (1u << 21) +
            (((unsigned)(b * 1024 + n0)) * 64 + e) * 4) = acc;
}

extern "C" void kernel_launch(void* const* d_in, const int* in_sizes, int n_in,
                              void* d_out, int out_size, void* d_ws, size_t ws_size,
                              hipStream_t stream) {
  (void)in_sizes; (void)n_in; (void)out_size; (void)ws_size;
  const float* ze     = (const float*)d_in[0];
  const float* cprobs = (const float*)d_in[1];
  const float* books  = (const float*)d_in[2];
  const float* lpq    = (const float*)d_in[3];
  const float* gum    = (const float*)d_in[4];
  float* out = (float*)d_out;
  char* ws = (char*)d_ws;
  hipLaunchKernelGGL(prep_ze_k,    dim3(32),   dim3(256), 0, stream, ze, ws);
  hipLaunchKernelGGL(prep_bnorm_k, dim3(32),   dim3(256), 0, stream, books, lpq, ws, out);
  hipLaunchKernelGGL(prep_b1_k,    dim3(256),  dim3(256), 0, stream, books, ws);
  hipLaunchKernelGGL(prep_b2_k,    dim3(256),  dim3(256), 0, stream, books, ws);
  hipLaunchKernelGGL(gvq_main,     dim3(1024), dim3(512), 0, stream, gum, cprobs, lpq, ws, out);
  hipLaunchKernelGGL(zq_red_k,     dim3(512),  dim3(256), 0, stream, ws, out);
}

// Round 17
// 233.069 us; speedup vs baseline: 1.5094x; 1.0156x over previous
//
#include <hip/hip_runtime.h>
#include <hip/hip_bf16.h>

typedef __attribute__((ext_vector_type(8))) short short8;
typedef __attribute__((ext_vector_type(4))) float f32x4;
typedef __attribute__((ext_vector_type(2))) float f32x2;

// ---- workspace layout (bytes) ----
#define WS_ZE     0u
#define WS_ZELO   (1u<<20)
#define WS_B1H    (2u<<20)
#define WS_B1L    (3u<<20)
#define WS_B2     (4u<<20)
#define WS_ZN2    (5u<<20)
#define WS_BS2    ((5u<<20)+32768u)
#define WS_ZQP    (6u<<20)     // 3 x 2 MB partials

__device__ __forceinline__ unsigned short f2bf(float x) {
  __hip_bfloat16 h = __float2bfloat16(x);
  return __builtin_bit_cast(unsigned short, h);
}
__device__ __forceinline__ float bf2f(unsigned short u) {
  union { unsigned int i; float f; } x; x.i = ((unsigned int)u) << 16; return x.f;
}
// LDS-only barrier: does NOT drain vmcnt -> global stores stay in flight
__device__ __forceinline__ void lds_barrier() {
  asm volatile("s_waitcnt lgkmcnt(0)" ::: "memory");
  __builtin_amdgcn_s_barrier();
}

// ---------------- merged prep: ze / bnorm / b1 / b2 by block range ----------------
__global__ __launch_bounds__(256) void prep_all_k(const float* __restrict__ ze,
                                                  const float* __restrict__ books,
                                                  const float* __restrict__ lpq,
                                                  char* __restrict__ ws,
                                                  float* __restrict__ d_out) {
  const int bb = blockIdx.x;
  if (bb < 32) {
    // ---- ze -> bf16 hi/lo + row norms ----
    int t = bb * 256 + threadIdx.x;
    const f32x4* row = (const f32x4*)(ze + t * 64);
    unsigned short* dh = (unsigned short*)(ws + WS_ZE) + t * 64;
    unsigned short* dl = (unsigned short*)(ws + WS_ZELO) + t * 64;
    float s = 0.f;
#pragma unroll
    for (int c = 0; c < 8; ++c) {
      const f32x4 v0 = row[2 * c], v1 = row[2 * c + 1];
      union { unsigned short u[8]; short8 v; } H, L;
#pragma unroll
      for (int r = 0; r < 4; ++r) {
        float a = v0[r]; s += a * a;
        unsigned short h = f2bf(a); H.u[r] = h; L.u[r] = f2bf(a - bf2f(h));
        float b = v1[r]; s += b * b;
        unsigned short h2 = f2bf(b); H.u[4 + r] = h2; L.u[4 + r] = f2bf(b - bf2f(h2));
      }
      *(short8*)(dh + c * 8) = H.v;
      *(short8*)(dl + c * 8) = L.v;
    }
    ((float*)(ws + WS_ZN2))[t] = s;
  } else if (bb < 64) {
    // ---- book norms + precision ----
    int t = (bb - 32) * 256 + threadIdx.x;
    if (t == 0) d_out[524288] = 0.5f / fmaxf(expf(lpq[0]), 1e-10f);
    const f32x4* row = (const f32x4*)(books + t * 64);
    float s = 0.f;
#pragma unroll
    for (int c = 0; c < 16; ++c) {
      const f32x4 v = row[c];
#pragma unroll
      for (int r = 0; r < 4; ++r) s += v[r] * v[r];
    }
    ((float*)(ws + WS_BS2))[t] = s;
  } else if (bb < 320) {
    // ---- matmul1 A-frag images ----
    int t = (bb - 64) * 256 + threadIdx.x;
    const int sl = t & 15, g = (t >> 4) & 3, f = (t >> 6) & 1, tt = (t >> 7) & 31, k = t >> 12;
    const float* src = books + ((k * 512 + tt * 16 + sl) * 64 + f * 32 + g * 8);
    const f32x4 v0 = *(const f32x4*)(src);
    const f32x4 v1 = *(const f32x4*)(src + 4);
    union { unsigned short u[8]; short8 v; } H, L;
#pragma unroll
    for (int r = 0; r < 4; ++r) {
      unsigned short h = f2bf(v0[r]); H.u[r] = h; L.u[r] = f2bf(v0[r] - bf2f(h));
      unsigned short h2 = f2bf(v1[r]); H.u[4 + r] = h2; L.u[4 + r] = f2bf(v1[r] - bf2f(h2));
    }
    const int off = (k * 32 + tt) * 2048 + f * 1024 + (sl + g * 16) * 16;
    *(short8*)(ws + WS_B1H + off) = H.v;
    *(short8*)(ws + WS_B1L + off) = L.v;
  } else {
    // ---- matmul2 A-frag image ----
    int t = (bb - 320) * 256 + threadIdx.x;
    const int l15 = t & 15, sub = (t >> 4) & 3, m = (t >> 6) & 3, w = (t >> 8) & 7,
              hh = (t >> 11) & 1, k = t >> 12;
    const float* src = books + ((k * 512 + hh * 256 + w * 32 + sub * 8) * 64 + m * 16 + l15);
    union { unsigned short u[8]; short8 v; } H;
#pragma unroll
    for (int j = 0; j < 8; ++j) H.u[j] = f2bf(src[j * 64]);
    *(short8*)(ws + WS_B2 + k * 65536 + ((hh * 8 + w) * 4 + m) * 1024 + (l15 + sub * 16) * 16) = H.v;
  }
}

// ---------------- zq partial reduce (3 partials) ----------------
__global__ __launch_bounds__(256) void zq_red_k(const char* __restrict__ ws,
                                                float* __restrict__ d_out) {
  int t = blockIdx.x * 256 + threadIdx.x;
  const f32x4 a = *(const f32x4*)(ws + WS_ZQP + t * 16);
  const f32x4 b = *(const f32x4*)(ws + WS_ZQP + (2u << 20) + t * 16);
  const f32x4 c = *(const f32x4*)(ws + WS_ZQP + (4u << 20) + t * 16);
  *(f32x4*)(d_out + t * 4) = a + b + c;
}

// ---------------- main: 3-way k-split (grid=1536 = 2 clean rounds of 768) ----------------
// LDS: logits f32 [16][516] (2064B) = 33024 + enc bf16 [16][536] (1072B) = 17152 + esc 64 = 50240 B
__global__ __launch_bounds__(512, 3)
void gvq_main(const float* __restrict__ gum, const float* __restrict__ cprobs,
              const float* __restrict__ lpq, char* __restrict__ ws,
              float* __restrict__ d_out) {
  __shared__ char lds[50240];
  char* lgb  = lds;                    // logits tile
  char* encb = lds + 33024;            // enc tile (unscaled e2)
  float* scr_esc = (float*)(lds + 50176);  // [16] per-row esc = cp/z2

  const int tid  = threadIdx.x;
  const int lane = tid & 63;
  const int wave = tid >> 6;
  const int l15  = lane & 15;
  const int g4   = lane >> 4;

  const int bid = blockIdx.x;      // 1536 blocks
  const unsigned kg = (unsigned)bid % 3u;
  const int bt  = (int)((unsigned)bid / 3u);   // 0..511
  const int b   = bt >> 6;
  const int n0  = (bt & 63) * 16;
  const int kbeg = (kg == 0) ? 0 : (kg == 1 ? 6 : 11);
  const int kcnt = (kg == 0) ? 6 : 5;

  const float prec  = 0.5f / fmaxf(expf(lpq[0]), 1e-10f);
  const float prec2 = 2.0f * prec;
  const float C24   = 3.7751345442790977e-11f;   // exp(-24)

  const unsigned short* zh = (const unsigned short*)(ws + WS_ZE)   + (b * 1024 + n0 + l15) * 64;
  const unsigned short* zl = (const unsigned short*)(ws + WS_ZELO) + (b * 1024 + n0 + l15) * 64;
  const short8 zf0h = *(const short8*)(zh + g4 * 8);
  const short8 zf1h = *(const short8*)(zh + 32 + g4 * 8);
  const short8 zf0l = *(const short8*)(zl + g4 * 8);
  const short8 zf1l = *(const short8*)(zl + 32 + g4 * 8);
  const float zn2p = ((const float*)(ws + WS_ZN2))[b * 1024 + n0 + l15] * prec;

  f32x4 zacc[4] = {{0,0,0,0},{0,0,0,0},{0,0,0,0},{0,0,0,0}};

  const int nr0 = wave * 2, nr1 = wave * 2 + 1;

#pragma unroll 1
  for (int kk = 0; kk < kcnt; ++kk) {
    const int k = kbeg + kk;
    const float cp = cprobs[b * 16 + k];
    const char* b1h = ws + WS_B1H + k * 65536;
    const char* b1l = ws + WS_B1L + k * 65536;
    const char* b2  = ws + WS_B2  + k * 65536;
    const float* bs2k = (const float*)(ws + WS_BS2) + k * 512;
    const long row0 = ((long)((b * 16 + k) * 1024) + n0 + nr0) * 512;
    const long row1 = ((long)((b * 16 + k) * 1024) + n0 + nr1) * 512;

    // ---- phase A: logits -> LDS tile (padded rows) ----
#pragma unroll
    for (int i = 0; i < 4; ++i) {
      const int t = wave * 4 + i;
      const char* bh = b1h + t * 2048 + lane * 16;
      const char* bl = b1l + t * 2048 + lane * 16;
      const short8 a0h = *(const short8*)(bh);
      const short8 a1h = *(const short8*)(bh + 1024);
      const short8 a0l = *(const short8*)(bl);
      const short8 a1l = *(const short8*)(bl + 1024);
      f32x4 c = {0.f, 0.f, 0.f, 0.f};
      c = __builtin_amdgcn_mfma_f32_16x16x32_bf16(a0h, zf0h, c, 0, 0, 0);
      c = __builtin_amdgcn_mfma_f32_16x16x32_bf16(a1h, zf1h, c, 0, 0, 0);
      c = __builtin_amdgcn_mfma_f32_16x16x32_bf16(a0h, zf0l, c, 0, 0, 0);
      c = __builtin_amdgcn_mfma_f32_16x16x32_bf16(a1h, zf1l, c, 0, 0, 0);
      c = __builtin_amdgcn_mfma_f32_16x16x32_bf16(a0l, zf0h, c, 0, 0, 0);
      c = __builtin_amdgcn_mfma_f32_16x16x32_bf16(a1l, zf1h, c, 0, 0, 0);
      const f32x4 bs2v = *(const f32x4*)(bs2k + t * 16 + g4 * 4);
      f32x4 lv;
#pragma unroll
      for (int r = 0; r < 4; ++r)
        lv[r] = fmaf(c[r], prec2, fmaf(bs2v[r], -prec, -zn2p));
      *(f32x4*)(lgb + l15 * 2064 + (t * 16 + g4 * 4) * 4) = lv;
    }

    // ---- gumbel loads issued here: in flight across barrier + max-reduce ----
    float uv0[8], uv1[8];
#pragma unroll
    for (int j = 0; j < 8; ++j)
      uv0[j] = __builtin_nontemporal_load(gum + row0 + j * 64 + lane);
#pragma unroll
    for (int j = 0; j < 8; ++j)
      uv1[j] = __builtin_nontemporal_load(gum + row1 + j * 64 + lane);

    lds_barrier();                      // barrier 1: logits ready

    // ---- phase B: 2 full rows per wave; all streams dword-coalesced ----
#pragma unroll
    for (int r = 0; r < 2; ++r) {
      const int n = r ? nr1 : nr0;
      const long rowb = r ? row1 : row0;
      float Lv[8], e1[8];
      const float* l32 = (const float*)(lgb + n * 2064);
#pragma unroll
      for (int j = 0; j < 8; ++j) Lv[j] = l32[j * 64 + lane];

      // full-row max
      float m = Lv[0];
#pragma unroll
      for (int j = 1; j < 8; ++j) m = fmaxf(m, Lv[j]);
#pragma unroll
      for (int o = 1; o < 64; o <<= 1) m = fmaxf(m, __shfl_xor(m, o));

      // e1; e2 unscaled (bound-max m2 = 2m+24) packed straight to LDS
      unsigned short* er = (unsigned short*)(encb + n * 1072);
      float z1 = 0.f, z2 = 0.f;
#pragma unroll
      for (int j = 0; j < 8; ++j) {
        const float u = r ? uv1[j] : uv0[j];
        e1[j] = __expf(Lv[j] - m); z1 += e1[j];
        const float L  = 1e-10f - __logf(u + 1e-10f);
        const float rl = __builtin_amdgcn_rcpf(L);
        const float e2 = (e1[j] * e1[j]) * (rl * rl) * C24;
        z2 += e2;
        er[j * 64 + lane] = f2bf(e2);
      }
#pragma unroll
      for (int o = 1; o < 64; o <<= 1) {
        z1 += __shfl_xor(z1, o);
        z2 += __shfl_xor(z2, o);
      }
      const float rz1 = 1.0f / z1;
      const float c1  = m + __logf(z1);
      if (lane == 0) scr_esc[n] = cp / z2;   // per-row enc scale, applied in phase C

      // dword nt-stores: wave-contiguous 256B, alignment-immune
      float* pp = d_out + 524289 + rowb;
      float* pl = pp + 67108864;
#pragma unroll
      for (int j = 0; j < 8; ++j)
        __builtin_nontemporal_store(e1[j] * rz1, pp + j * 64 + lane);
#pragma unroll
      for (int j = 0; j < 8; ++j)
        __builtin_nontemporal_store(Lv[j] - c1, pl + j * 64 + lane);
    }
    lds_barrier();                      // barrier 2: enc + esc ready

    // ---- phase C: cacc = booksT . encT (both h), then zacc += cacc * esc[l15] ----
    {
      f32x4 cacc[4] = {{0,0,0,0},{0,0,0,0},{0,0,0,0},{0,0,0,0}};
#pragma unroll
      for (int h = 0; h < 2; ++h) {
        const short8 bf = *(const short8*)(encb + l15 * 1072 +
                                           (h * 256 + wave * 32 + g4 * 8) * 2);
        const char* afb = b2 + ((h * 8 + wave) * 4) * 1024 + lane * 16;
#pragma unroll
        for (int m = 0; m < 4; ++m) {
          const short8 af = *(const short8*)(afb + m * 1024);
          cacc[m] = __builtin_amdgcn_mfma_f32_16x16x32_bf16(af, bf, cacc[m], 0, 0, 0);
        }
      }
      const float esc = scr_esc[l15];   // output col = l15 = n -> lane-local scale
#pragma unroll
      for (int m = 0; m < 4; ++m)
#pragma unroll
        for (int r = 0; r < 4; ++r) zacc[m][r] = fmaf(cacc[m][r], esc, zacc[m][r]);
    }
  }

  // ---- zq cross-wave reduce + partial write ----
  __syncthreads();
#pragma unroll
  for (int m = 0; m < 4; ++m)
    *(f32x4*)(lds + wave * 4096 + l15 * 256 + m * 64 + g4 * 16) = zacc[m];
  __syncthreads();
  const int e = tid * 2;
  f32x2 acc = {0.f, 0.f};
#pragma unroll
  for (int w = 0; w < 8; ++w) acc += *(const f32x2*)(lds + w * 4096 + e * 4);
  *(f32x2*)(ws + WS_ZQP + kg * (2u << 20) +
            (((unsigned)(b * 1024 + n0)) * 64 + e) * 4) = acc;
}

extern "C" void kernel_launch(void* const* d_in, const int* in_sizes, int n_in,
                              void* d_out, int out_size, void* d_ws, size_t ws_size,
                              hipStream_t stream) {
  (void)in_sizes; (void)n_in; (void)out_size; (void)ws_size;
  const float* ze     = (const float*)d_in[0];
  const float* cprobs = (const float*)d_in[1];
  const float* books  = (const float*)d_in[2];
  const float* lpq    = (const float*)d_in[3];
  const float* gum    = (const float*)d_in[4];
  float* out = (float*)d_out;
  char* ws = (char*)d_ws;
  hipLaunchKernelGGL(prep_all_k, dim3(576),  dim3(256), 0, stream, ze, books, lpq, ws, out);
  hipLaunchKernelGGL(gvq_main,   dim3(1536), dim3(512), 0, stream, gum, cprobs, lpq, ws, out);
  hipLaunchKernelGGL(zq_red_k,   dim3(512),  dim3(256), 0, stream, ws, out);
}

// Round 18
// 230.525 us; speedup vs baseline: 1.5260x; 1.0110x over previous
//
#include <hip/hip_runtime.h>
#include <hip/hip_bf16.h>

typedef __attribute__((ext_vector_type(8))) short short8;
typedef __attribute__((ext_vector_type(4))) float f32x4;
typedef __attribute__((ext_vector_type(2))) float f32x2;

// ---- workspace layout (bytes), 12 MB total ----
#define WS_ZE     0u            // bf16 ze-hi [B][N][64] : 1 MB
#define WS_B1H    (1u<<20)      // matmul1 A-frag image (hi): 1 MB
#define WS_B2     (2u<<20)      // matmul2 A-frag image (hi): 1 MB
#define WS_ZN2    (3u<<20)      // f32 [B][N] 32 KB
#define WS_BS2    ((3u<<20)+32768u) // f32 [K][S] 32 KB
#define WS_ZQP    (4u<<20)      // f32 partial zq: 4 x 2 MB

__device__ __forceinline__ unsigned short f2bf(float x) {
  __hip_bfloat16 h = __float2bfloat16(x);
  return __builtin_bit_cast(unsigned short, h);
}
// LDS-only barrier: does NOT drain vmcnt -> global stores stay in flight
__device__ __forceinline__ void lds_barrier() {
  asm volatile("s_waitcnt lgkmcnt(0)" ::: "memory");
  __builtin_amdgcn_s_barrier();
}

// ---------------- merged prep: ze / bnorm / b1 / b2 by block range ----------------
__global__ __launch_bounds__(256) void prep_all_k(const float* __restrict__ ze,
                                                  const float* __restrict__ books,
                                                  const float* __restrict__ lpq,
                                                  char* __restrict__ ws,
                                                  float* __restrict__ d_out) {
  const int bb = blockIdx.x;
  if (bb < 32) {
    // ---- ze -> bf16 hi + row norms ----
    int t = bb * 256 + threadIdx.x;
    const f32x4* row = (const f32x4*)(ze + t * 64);
    unsigned short* dh = (unsigned short*)(ws + WS_ZE) + t * 64;
    float s = 0.f;
#pragma unroll
    for (int c = 0; c < 8; ++c) {
      const f32x4 v0 = row[2 * c], v1 = row[2 * c + 1];
      union { unsigned short u[8]; short8 v; } H;
#pragma unroll
      for (int r = 0; r < 4; ++r) {
        float a = v0[r]; s += a * a; H.u[r] = f2bf(a);
        float b = v1[r]; s += b * b; H.u[4 + r] = f2bf(b);
      }
      *(short8*)(dh + c * 8) = H.v;
    }
    ((float*)(ws + WS_ZN2))[t] = s;
  } else if (bb < 64) {
    // ---- book norms + precision ----
    int t = (bb - 32) * 256 + threadIdx.x;
    if (t == 0) d_out[524288] = 0.5f / fmaxf(expf(lpq[0]), 1e-10f);
    const f32x4* row = (const f32x4*)(books + t * 64);
    float s = 0.f;
#pragma unroll
    for (int c = 0; c < 16; ++c) {
      const f32x4 v = row[c];
#pragma unroll
      for (int r = 0; r < 4; ++r) s += v[r] * v[r];
    }
    ((float*)(ws + WS_BS2))[t] = s;
  } else if (bb < 320) {
    // ---- matmul1 A-frag image (hi only) ----
    int t = (bb - 64) * 256 + threadIdx.x;
    const int sl = t & 15, g = (t >> 4) & 3, f = (t >> 6) & 1, tt = (t >> 7) & 31, k = t >> 12;
    const float* src = books + ((k * 512 + tt * 16 + sl) * 64 + f * 32 + g * 8);
    const f32x4 v0 = *(const f32x4*)(src);
    const f32x4 v1 = *(const f32x4*)(src + 4);
    union { unsigned short u[8]; short8 v; } H;
#pragma unroll
    for (int r = 0; r < 4; ++r) { H.u[r] = f2bf(v0[r]); H.u[4 + r] = f2bf(v1[r]); }
    *(short8*)(ws + WS_B1H + (k * 32 + tt) * 2048 + f * 1024 + (sl + g * 16) * 16) = H.v;
  } else {
    // ---- matmul2 A-frag image ----
    int t = (bb - 320) * 256 + threadIdx.x;
    const int l15 = t & 15, sub = (t >> 4) & 3, m = (t >> 6) & 3, w = (t >> 8) & 7,
              hh = (t >> 11) & 1, k = t >> 12;
    const float* src = books + ((k * 512 + hh * 256 + w * 32 + sub * 8) * 64 + m * 16 + l15);
    union { unsigned short u[8]; short8 v; } H;
#pragma unroll
    for (int j = 0; j < 8; ++j) H.u[j] = f2bf(src[j * 64]);
    *(short8*)(ws + WS_B2 + k * 65536 + ((hh * 8 + w) * 4 + m) * 1024 + (l15 + sub * 16) * 16) = H.v;
  }
}

// ---------------- zq partial reduce (4 partials) ----------------
__global__ __launch_bounds__(256) void zq_red_k(const char* __restrict__ ws,
                                                float* __restrict__ d_out) {
  int t = blockIdx.x * 256 + threadIdx.x;
  const f32x4 a = *(const f32x4*)(ws + WS_ZQP + t * 16);
  const f32x4 b = *(const f32x4*)(ws + WS_ZQP + (2u << 20) + t * 16);
  const f32x4 c = *(const f32x4*)(ws + WS_ZQP + (4u << 20) + t * 16);
  const f32x4 d = *(const f32x4*)(ws + WS_ZQP + (6u << 20) + t * 16);
  *(f32x4*)(d_out + t * 4) = (a + b) + (c + d);
}

// ---------------- main: bf16-grade, 4 blocks/CU, enc aliased into logits tile ----------------
// LDS: logits f32 [16] rows x 2064 B (enc bf16 overlays first 1024 B of each row) + esc 64 = 33088 B
__global__ __launch_bounds__(512, 4)
void gvq_main(const float* __restrict__ gum, const float* __restrict__ cprobs,
              const float* __restrict__ lpq, char* __restrict__ ws,
              float* __restrict__ d_out) {
  __shared__ char lds[33088];
  char* lgb = lds;                          // logits tile rows (enc aliases row head)
  float* scr_esc = (float*)(lds + 33024);   // [16] per-row esc = cp/z2

  const int tid  = threadIdx.x;
  const int lane = tid & 63;
  const int wave = tid >> 6;
  const int l15  = lane & 15;
  const int g4   = lane >> 4;

  const int bid = blockIdx.x;               // 2048 blocks
  const unsigned kg = ((unsigned)bid & 7u) >> 1;          // XCD-pair-aligned k-group
  const int bt  = ((bid >> 3) << 1) | (bid & 1);          // 0..511
  const int b   = bt >> 6;
  const int n0  = (bt & 63) * 16;
  const int kbeg = (int)kg * 4;

  const float prec  = 0.5f / fmaxf(expf(lpq[0]), 1e-10f);
  const float prec2 = 2.0f * prec;
  const float C24   = 3.7751345442790977e-11f;   // exp(-24)

  const unsigned short* zh = (const unsigned short*)(ws + WS_ZE) + (b * 1024 + n0 + l15) * 64;
  const short8 zf0h = *(const short8*)(zh + g4 * 8);
  const short8 zf1h = *(const short8*)(zh + 32 + g4 * 8);
  const float zn2p = ((const float*)(ws + WS_ZN2))[b * 1024 + n0 + l15] * prec;

  f32x4 zacc[4] = {{0,0,0,0},{0,0,0,0},{0,0,0,0},{0,0,0,0}};

  const int nr0 = wave * 2, nr1 = wave * 2 + 1;

#pragma unroll 1
  for (int kk = 0; kk < 4; ++kk) {
    const int k = kbeg + kk;
    const float cp = cprobs[b * 16 + k];
    const char* b1h = ws + WS_B1H + k * 65536;
    const char* b2  = ws + WS_B2  + k * 65536;
    const float* bs2k = (const float*)(ws + WS_BS2) + k * 512;
    const long row0 = ((long)((b * 16 + k) * 1024) + n0 + nr0) * 512;
    const long row1 = ((long)((b * 16 + k) * 1024) + n0 + nr1) * 512;

    // ---- phase A: bf16 logits -> LDS tile ----
#pragma unroll
    for (int i = 0; i < 4; ++i) {
      const int t = wave * 4 + i;
      const char* bh = b1h + t * 2048 + lane * 16;
      const short8 a0h = *(const short8*)(bh);
      const short8 a1h = *(const short8*)(bh + 1024);
      f32x4 c = {0.f, 0.f, 0.f, 0.f};
      c = __builtin_amdgcn_mfma_f32_16x16x32_bf16(a0h, zf0h, c, 0, 0, 0);
      c = __builtin_amdgcn_mfma_f32_16x16x32_bf16(a1h, zf1h, c, 0, 0, 0);
      const f32x4 bs2v = *(const f32x4*)(bs2k + t * 16 + g4 * 4);
      f32x4 lv;
#pragma unroll
      for (int r = 0; r < 4; ++r)
        lv[r] = fmaf(c[r], prec2, fmaf(bs2v[r], -prec, -zn2p));
      *(f32x4*)(lgb + l15 * 2064 + (t * 16 + g4 * 4) * 4) = lv;
    }
    lds_barrier();                      // barrier 1: logits ready

    // ---- phase B: 2 full rows per wave; dword nt streams ----
#pragma unroll
    for (int r = 0; r < 2; ++r) {
      const int n = r ? nr1 : nr0;
      const long rowb = r ? row1 : row0;
      // gumbel loads for this row (latency covered by Lv reads + max reduce)
      float uv[8];
#pragma unroll
      for (int j = 0; j < 8; ++j)
        uv[j] = __builtin_nontemporal_load(gum + rowb + j * 64 + lane);

      float Lv[8];
      const float* l32 = (const float*)(lgb + n * 2064);
#pragma unroll
      for (int j = 0; j < 8; ++j) Lv[j] = l32[j * 64 + lane];

      // full-row max
      float m = Lv[0];
#pragma unroll
      for (int j = 1; j < 8; ++j) m = fmaxf(m, Lv[j]);
#pragma unroll
      for (int o = 1; o < 64; o <<= 1) m = fmaxf(m, __shfl_xor(m, o));

      // e1 (transient); e2 unscaled (bound-max m2 = 2m+24) -> enc aliased in row head
      unsigned short* er = (unsigned short*)(lgb + n * 2064);
      float z1 = 0.f, z2 = 0.f;
#pragma unroll
      for (int j = 0; j < 8; ++j) {
        const float e1 = __expf(Lv[j] - m); z1 += e1;
        const float L  = 1e-10f - __logf(uv[j] + 1e-10f);
        const float rl = __builtin_amdgcn_rcpf(L);
        const float e2 = (e1 * e1) * (rl * rl) * C24;
        z2 += e2;
        er[j * 64 + lane] = f2bf(e2);
      }
#pragma unroll
      for (int o = 1; o < 64; o <<= 1) {
        z1 += __shfl_xor(z1, o);
        z2 += __shfl_xor(z2, o);
      }
      const float c1 = m + __logf(z1);
      if (lane == 0) scr_esc[n] = cp / z2;

      // dword nt-stores: wave-contiguous, alignment-immune
      float* pp = d_out + 524289 + rowb;
      float* pl = pp + 67108864;
#pragma unroll
      for (int j = 0; j < 8; ++j) {
        const float lpv = Lv[j] - c1;
        __builtin_nontemporal_store(__expf(lpv), pp + j * 64 + lane);
        __builtin_nontemporal_store(lpv, pl + j * 64 + lane);
      }
    }
    lds_barrier();                      // barrier 2: enc + esc ready

    // ---- phase C: cacc = booksT . encT, zacc += cacc * esc[l15] ----
    {
      f32x4 cacc[4] = {{0,0,0,0},{0,0,0,0},{0,0,0,0},{0,0,0,0}};
#pragma unroll
      for (int h = 0; h < 2; ++h) {
        const short8 bf = *(const short8*)(lgb + l15 * 2064 +
                                           (h * 256 + wave * 32 + g4 * 8) * 2);
        const char* afb = b2 + ((h * 8 + wave) * 4) * 1024 + lane * 16;
#pragma unroll
        for (int m = 0; m < 4; ++m) {
          const short8 af = *(const short8*)(afb + m * 1024);
          cacc[m] = __builtin_amdgcn_mfma_f32_16x16x32_bf16(af, bf, cacc[m], 0, 0, 0);
        }
      }
      const float esc = scr_esc[l15];
#pragma unroll
      for (int m = 0; m < 4; ++m)
#pragma unroll
        for (int r = 0; r < 4; ++r) zacc[m][r] = fmaf(cacc[m][r], esc, zacc[m][r]);
    }
    lds_barrier();                      // barrier 3: enc reads done before next A overwrites
  }

  // ---- zq cross-wave reduce + partial write ----
  __syncthreads();
#pragma unroll
  for (int m = 0; m < 4; ++m)
    *(f32x4*)(lds + wave * 4096 + l15 * 256 + m * 64 + g4 * 16) = zacc[m];
  __syncthreads();
  const int e = tid * 2;
  f32x2 acc = {0.f, 0.f};
#pragma unroll
  for (int w = 0; w < 8; ++w) acc += *(const f32x2*)(lds + w * 4096 + e * 4);
  *(f32x2*)(ws + WS_ZQP + kg * (2u << 20) +
            (((unsigned)(b * 1024 + n0)) * 64 + e) * 4) = acc;
}

extern "C" void kernel_launch(void* const* d_in, const int* in_sizes, int n_in,
                              void* d_out, int out_size, void* d_ws, size_t ws_size,
                              hipStream_t stream) {
  (void)in_sizes; (void)n_in; (void)out_size; (void)ws_size;
  const float* ze     = (const float*)d_in[0];
  const float* cprobs = (const float*)d_in[1];
  const float* books  = (const float*)d_in[2];
  const float* lpq    = (const float*)d_in[3];
  const float* gum    = (const float*)d_in[4];
  float* out = (float*)d_out;
  char* ws = (char*)d_ws;
  hipLaunchKernelGGL(prep_all_k, dim3(576),  dim3(256), 0, stream, ze, books, lpq, ws, out);
  hipLaunchKernelGGL(gvq_main,   dim3(2048), dim3(512), 0, stream, gum, cprobs, lpq, ws, out);
  hipLaunchKernelGGL(zq_red_k,   dim3(512),  dim3(256), 0, stream, ws, out);
}